// Round 8
// baseline (665.859 us; speedup 1.0000x reference)
//
#include <hip/hip_runtime.h>
#include <hip/hip_bf16.h>
#include <math.h>

#define NN 100000
#define CC 128
#define EE 1600000
#define SCAN_CHUNK 2048
#define NB_SCAN ((NN + SCAN_CHUNK - 1) / SCAN_CHUNK)  // 49
#define NRANGE 8
#define RNODES (NN / NRANGE)     // 12500
#define EPT 8                    // edges per thread in bucket kernel
#define FCHUNK (256 * EPT)       // 2048 edges per block
#define NCHUNKS ((EE + FCHUNK - 1) / FCHUNK)  // 782
#define BCAP 384                 // per-range LDS staging capacity (int2)
#define BUCKET_CAP 220000        // per-range global bucket capacity (mean 200K, +47 sigma)
#define RB 96                    // blocks per range for hist/fill from buckets

typedef short  bf16x8 __attribute__((ext_vector_type(8)));
typedef float  f32x4  __attribute__((ext_vector_type(4)));
typedef unsigned short u16x8 __attribute__((ext_vector_type(8)));

#define TPAD 132   // float stride for per-wave T tiles (528 B, 16B-aligned)

__device__ __forceinline__ ushort f2bf(float f) {
    __hip_bfloat16 h = __float2bfloat16(f);   // RNE
    return __builtin_bit_cast(ushort, h);
}
__device__ __forceinline__ float bf2f(ushort u) {
    return __builtin_bit_cast(float, ((unsigned int)u) << 16);
}

// ===========================================================================
// Phase A: single-pass bucket sort of edges by dst range.
// LDS-staged so global bucket appends are coalesced full-line int2 writes.
// ===========================================================================
__global__ void __launch_bounds__(256) bucket_edges(
    const int* __restrict__ src, const int* __restrict__ dst,
    int* __restrict__ bucketCnt, int2* __restrict__ bucketBuf)
{
    __shared__ int2 stage[NRANGE][BCAP];
    __shared__ int lcnt[NRANGE];
    __shared__ int lbase[NRANGE];
    __shared__ int remaining;

    const int tid = threadIdx.x;
    int base = blockIdx.x * FCHUNK + tid * EPT;
    int2 ed[EPT];
    int  rg[EPT];
    bool placed[EPT];
#pragma unroll
    for (int i = 0; i < EPT; ++i) {
        int e = base + i;
        if (e < EE) {
            ed[i].x = src[e];
            ed[i].y = dst[e];
            rg[i] = ed[i].y / RNODES;
            placed[i] = false;
        } else {
            placed[i] = true;
        }
    }

    while (true) {
        if (tid < NRANGE) lcnt[tid] = 0;
        if (tid == 0) remaining = 0;
        __syncthreads();
        int u = 0;
#pragma unroll
        for (int i = 0; i < EPT; ++i) {
            if (!placed[i]) {
                int p = atomicAdd(&lcnt[rg[i]], 1);
                if (p < BCAP) { stage[rg[i]][p] = ed[i]; placed[i] = true; }
                else u++;
            }
        }
        if (u) atomicAdd(&remaining, u);
        __syncthreads();
        if (tid == 0) {
#pragma unroll
            for (int r = 0; r < NRANGE; ++r) {
                int c = lcnt[r]; if (c > BCAP) c = BCAP;
                lbase[r] = atomicAdd(&bucketCnt[r], c);
            }
        }
        __syncthreads();
#pragma unroll
        for (int r = 0; r < NRANGE; ++r) {
            int c = lcnt[r]; if (c > BCAP) c = BCAP;
            int b = lbase[r];
            for (int i = tid; i < c; i += 256) {
                int idx = b + i;
                if (idx < BUCKET_CAP)
                    bucketBuf[(size_t)r * BUCKET_CAP + idx] = stage[r][i];
            }
        }
        int rem = remaining;
        __syncthreads();   // protect stage/lcnt reuse and remaining re-init
        if (rem == 0) break;
    }
}

// ===========================================================================
// Phase B: hist + fill reading only the per-range bucket (L2-resident targets,
// no streaming eviction pressure; blocks b&7==r pin a range to one XCD).
// ===========================================================================
__global__ void __launch_bounds__(256) hist_bucket(
    const int2* __restrict__ bucketBuf, const int* __restrict__ bucketCnt,
    int* __restrict__ deg)
{
    int r  = blockIdx.x & (NRANGE - 1);
    int bi = blockIdx.x >> 3;
    int cnt = bucketCnt[r];
    const int2* buf = bucketBuf + (size_t)r * BUCKET_CAP;
    for (int i = bi * 256 + threadIdx.x; i < cnt; i += RB * 256)
        atomicAdd(&deg[buf[i].y], 1);
}

__global__ void __launch_bounds__(256) fill_bucket(
    const int2* __restrict__ bucketBuf, const int* __restrict__ bucketCnt,
    int* __restrict__ cursor, int* __restrict__ col)
{
    int r  = blockIdx.x & (NRANGE - 1);
    int bi = blockIdx.x >> 3;
    int cnt = bucketCnt[r];
    const int2* buf = bucketBuf + (size_t)r * BUCKET_CAP;
    for (int i = bi * 256 + threadIdx.x; i < cnt; i += RB * 256) {
        int2 e = buf[i];
        int pos = atomicAdd(&cursor[e.y], 1);
        col[pos] = e.x;
    }
}

// ===========================================================================
// Scan (unchanged)
// ===========================================================================
__global__ void __launch_bounds__(256) deg_block_reduce(
    const int* __restrict__ deg, int* __restrict__ blockSums)
{
    int base = blockIdx.x * SCAN_CHUNK + threadIdx.x * 8;
    int s = 0;
#pragma unroll
    for (int i = 0; i < 8; ++i) {
        int idx = base + i;
        if (idx < NN) s += deg[idx];
    }
#pragma unroll
    for (int off = 32; off > 0; off >>= 1) s += __shfl_down(s, off);
    __shared__ int ws[4];
    int lane = threadIdx.x & 63, wid = threadIdx.x >> 6;
    if (lane == 0) ws[wid] = s;
    __syncthreads();
    if (threadIdx.x == 0) blockSums[blockIdx.x] = ws[0] + ws[1] + ws[2] + ws[3];
}

__global__ void scan_offsets(const int* __restrict__ blockSums,
                             int* __restrict__ blockOff, int* __restrict__ rowptr)
{
    int lane = threadIdx.x;  // 64 threads
    int v = (lane < NB_SCAN) ? blockSums[lane] : 0;
    int inc = v;
#pragma unroll
    for (int off = 1; off < 64; off <<= 1) {
        int n = __shfl_up(inc, off);
        if (lane >= off) inc += n;
    }
    if (lane < NB_SCAN) blockOff[lane] = inc - v;
    if (lane == 63) rowptr[NN] = EE;
}

__global__ void __launch_bounds__(256) deg_scan_write(
    const int* __restrict__ deg, const int* __restrict__ blockOff,
    int* __restrict__ rowptr, int* __restrict__ cursor)
{
    __shared__ int warpSums[4];
    int base = blockIdx.x * SCAN_CHUNK + threadIdx.x * 8;
    int v[8];
    int s = 0;
#pragma unroll
    for (int i = 0; i < 8; ++i) {
        int idx = base + i;
        v[i] = (idx < NN) ? deg[idx] : 0;
        s += v[i];
    }
    int lane = threadIdx.x & 63, wid = threadIdx.x >> 6;
    int inc = s;
#pragma unroll
    for (int off = 1; off < 64; off <<= 1) {
        int n = __shfl_up(inc, off);
        if (lane >= off) inc += n;
    }
    if (lane == 63) warpSums[wid] = inc;
    __syncthreads();
    int wofs = 0;
#pragma unroll
    for (int w = 0; w < 4; ++w)
        if (w < wid) wofs += warpSums[w];
    int exc = blockOff[blockIdx.x] + wofs + (inc - s);
#pragma unroll
    for (int i = 0; i < 8; ++i) {
        int idx = base + i;
        if (idx < NN) { rowptr[idx] = exc; cursor[idx] = exc; }
        exc += v[i];
    }
}

// ===========================================================================
// Conversions
// ===========================================================================
__global__ void __launch_bounds__(256) convert_x_kernel(
    const float* __restrict__ x, ushort* __restrict__ xb)
{
    int i = blockIdx.x * 256 + threadIdx.x;   // float4 groups; NN*CC/4 total
    float4 v = ((const float4*)x)[i];
    ushort4 o;
    o.x = f2bf(v.x); o.y = f2bf(v.y); o.z = f2bf(v.z); o.w = f2bf(v.w);
    ((ushort4*)xb)[i] = o;
}

__global__ void __launch_bounds__(256) convert_w6_kernel(
    const float* __restrict__ w0, const float* __restrict__ w1,
    const float* __restrict__ w2, const float* __restrict__ w3,
    const float* __restrict__ w4, const float* __restrict__ w5,
    ushort* __restrict__ wt)
{
    int i = blockIdx.x * 256 + threadIdx.x;  // 6*16384
    int mat = i >> 14;
    int rem = i & 16383;
    int k = rem >> 7, n = rem & 127;
    const float* w = (mat == 0) ? w0 : (mat == 1) ? w1 : (mat == 2) ? w2
                   : (mat == 3) ? w3 : (mat == 4) ? w4 : w5;
    wt[mat * 16384 + n * 128 + k] = f2bf(w[k * 128 + n]);
}

// ===========================================================================
// Standalone max-occupancy gather: agg[n] = h[n] + sum_nbr h[nbr]  (bf16)
// ===========================================================================
__global__ void __launch_bounds__(256) gather_agg(
    const ushort* __restrict__ hin, const int* __restrict__ rowptr,
    const int* __restrict__ col, ushort* __restrict__ agg)
{
    const int grp    = threadIdx.x >> 4;            // 0..15
    const int lane16 = threadIdx.x & 15;
    const int gbase  = (threadIdx.x & 63) & 48;     // group base lane in wave
    const int n = blockIdx.x * 16 + grp;            // 6250*16 = 100000 exact
    const u16x8* hp = (const u16x8*)hin;

    u16x8 self = hp[n * 16 + lane16];
    float s0[8], s1[8], s2[8], s3[8];
#pragma unroll
    for (int k = 0; k < 8; ++k) {
        s0[k] = bf2f(self[k]); s1[k] = 0.f; s2[k] = 0.f; s3[k] = 0.f;
    }

    int beg = rowptr[n], end = rowptr[n + 1];
    while (beg < end) {
        int take = end - beg;
        if (take > 16) take = 16;
        int ci = (lane16 < take) ? col[beg + lane16] : 0;
        int j = 0;
        for (; j + 4 <= take; j += 4) {
            int n0 = __shfl(ci, gbase + j + 0);
            int n1 = __shfl(ci, gbase + j + 1);
            int n2 = __shfl(ci, gbase + j + 2);
            int n3 = __shfl(ci, gbase + j + 3);
            u16x8 a0 = hp[n0 * 16 + lane16];
            u16x8 a1 = hp[n1 * 16 + lane16];
            u16x8 a2 = hp[n2 * 16 + lane16];
            u16x8 a3 = hp[n3 * 16 + lane16];
#pragma unroll
            for (int k = 0; k < 8; ++k) {
                s0[k] += bf2f(a0[k]); s1[k] += bf2f(a1[k]);
                s2[k] += bf2f(a2[k]); s3[k] += bf2f(a3[k]);
            }
        }
        for (; j < take; ++j) {
            int n0 = __shfl(ci, gbase + j);
            u16x8 a0 = hp[n0 * 16 + lane16];
#pragma unroll
            for (int k = 0; k < 8; ++k) s0[k] += bf2f(a0[k]);
        }
        beg += take;
    }

    bf16x8 o;
#pragma unroll
    for (int k = 0; k < 8; ++k) o[k] = (short)f2bf(s0[k] + s1[k] + s2[k] + s3[k]);
    *(bf16x8*)&((ushort*)agg)[n * CC + lane16 * 8] = o;
}

// ===========================================================================
// Barrier-free 2-tile per-wave MFMA MLP: each wave owns 32 rows (2 M-tiles).
// Every B-fragment load feeds 2 MFMAs (half the weight traffic per row,
// double the MFMA ILP). Per-wave private LDS T tile reused sequentially.
// ===========================================================================
template <bool FUSE_HEAD>
__global__ void __launch_bounds__(256, 4) mlp_wave2(
    const ushort* __restrict__ hin,
    const ushort* __restrict__ waT, const float* __restrict__ ba,
    const ushort* __restrict__ wbT, const float* __restrict__ bb,
    ushort* __restrict__ hout,
    const float* __restrict__ lw, const float* __restrict__ lb,
    float* __restrict__ out)
{
    __shared__ float Tt[4][16 * TPAD];   // per-wave private 16x128 fp32 tile

    const int wave = threadIdx.x >> 6;
    const int lane = threadIdx.x & 63;
    const int quad = lane >> 4;
    const int l16  = lane & 15;
    const int wv = blockIdx.x * 4 + wave;       // wave index; each owns 32 rows
    if (wv * 32 >= NN) return;                  // NN % 32 == 0: all-or-nothing
    const int row0 = wv * 32;
    float* T = Tt[wave];

    // ---- stage-1 A fragments straight from global, both tiles ----
    bf16x8 af0[4], af1[4];
#pragma unroll
    for (int kk = 0; kk < 4; ++kk) {
        af0[kk] = *(const bf16x8*)&hin[(row0 + l16) * CC + kk * 32 + quad * 8];
        af1[kk] = *(const bf16x8*)&hin[(row0 + 16 + l16) * CC + kk * 32 + quad * 8];
    }

    // ---- stage 1: T = relu(A @ Wa + ba), shared B-frag for both tiles ----
    f32x4 acc0[8], acc1[8];
#pragma unroll
    for (int nt = 0; nt < 8; ++nt) {
        acc0[nt] = (f32x4){0.f, 0.f, 0.f, 0.f};
        acc1[nt] = (f32x4){0.f, 0.f, 0.f, 0.f};
    }
#pragma unroll
    for (int kk = 0; kk < 4; ++kk) {
#pragma unroll
        for (int nt = 0; nt < 8; ++nt) {
            bf16x8 bfrag = *(const bf16x8*)&waT[(nt * 16 + l16) * CC + kk * 32 + quad * 8];
            acc0[nt] = __builtin_amdgcn_mfma_f32_16x16x32_bf16(af0[kk], bfrag, acc0[nt], 0, 0, 0);
            acc1[nt] = __builtin_amdgcn_mfma_f32_16x16x32_bf16(af1[kk], bfrag, acc1[nt], 0, 0, 0);
        }
    }

    // ---- C-layout -> A-layout via per-wave T, sequential per tile ----
    bf16x8 a20[4], a21[4];
#pragma unroll
    for (int t = 0; t < 2; ++t) {
#pragma unroll
        for (int nt = 0; nt < 8; ++nt) {
            int colc = nt * 16 + l16;
            float bias = ba[colc];
#pragma unroll
            for (int r = 0; r < 4; ++r) {
                float v = (t == 0 ? acc0[nt][r] : acc1[nt][r]) + bias;
                T[(quad * 4 + r) * TPAD + colc] = fmaxf(v, 0.f);
            }
        }
        // within-wave LDS write->read ordering (compiler lgkmcnt), no barrier
#pragma unroll
        for (int kk = 0; kk < 4; ++kk) {
            const float* tp = &T[l16 * TPAD + kk * 32 + quad * 8];
            float4 t0 = *(const float4*)tp;
            float4 t1 = *(const float4*)(tp + 4);
            bf16x8 f;
            f[0] = (short)f2bf(t0.x); f[1] = (short)f2bf(t0.y);
            f[2] = (short)f2bf(t0.z); f[3] = (short)f2bf(t0.w);
            f[4] = (short)f2bf(t1.x); f[5] = (short)f2bf(t1.y);
            f[6] = (short)f2bf(t1.z); f[7] = (short)f2bf(t1.w);
            if (t == 0) a20[kk] = f; else a21[kk] = f;
        }
    }

    // ---- stage 2: out = elu(T @ Wb + bb), shared B-frag for both tiles ----
    f32x4 bcc0[8], bcc1[8];
#pragma unroll
    for (int nt = 0; nt < 8; ++nt) {
        bcc0[nt] = (f32x4){0.f, 0.f, 0.f, 0.f};
        bcc1[nt] = (f32x4){0.f, 0.f, 0.f, 0.f};
    }
#pragma unroll
    for (int kk = 0; kk < 4; ++kk) {
#pragma unroll
        for (int nt = 0; nt < 8; ++nt) {
            bf16x8 bfrag = *(const bf16x8*)&wbT[(nt * 16 + l16) * CC + kk * 32 + quad * 8];
            bcc0[nt] = __builtin_amdgcn_mfma_f32_16x16x32_bf16(a20[kk], bfrag, bcc0[nt], 0, 0, 0);
            bcc1[nt] = __builtin_amdgcn_mfma_f32_16x16x32_bf16(a21[kk], bfrag, bcc1[nt], 0, 0, 0);
        }
    }

#pragma unroll
    for (int t = 0; t < 2; ++t) {
        const int trow0 = row0 + t * 16;
        if (FUSE_HEAD) {
            float part[4] = {0.f, 0.f, 0.f, 0.f};
#pragma unroll
            for (int nt = 0; nt < 8; ++nt) {
                int colc = nt * 16 + l16;
                float bias = bb[colc];
                float w = lw[colc];
#pragma unroll
                for (int r = 0; r < 4; ++r) {
                    float v = (t == 0 ? bcc0[nt][r] : bcc1[nt][r]) + bias;
                    v = v > 0.f ? v : expm1f(v);
                    part[r] += v * w;
                }
            }
#pragma unroll
            for (int r = 0; r < 4; ++r) {
#pragma unroll
                for (int off = 8; off > 0; off >>= 1)
                    part[r] += __shfl_xor(part[r], off);
            }
            if (l16 == 0) {
                float lbv = lb[0];
#pragma unroll
                for (int r = 0; r < 4; ++r) {
                    int grow = trow0 + quad * 4 + r;
                    float z = part[r] + lbv;
                    out[grow] = 1.f / (1.f + expf(-z));
                }
            }
        } else {
            // elu -> T (safe: same wave done with a2 reads) -> coalesced store
#pragma unroll
            for (int nt = 0; nt < 8; ++nt) {
                int colc = nt * 16 + l16;
                float bias = bb[colc];
#pragma unroll
                for (int r = 0; r < 4; ++r) {
                    float v = (t == 0 ? bcc0[nt][r] : bcc1[nt][r]) + bias;
                    T[(quad * 4 + r) * TPAD + colc] = v > 0.f ? v : expm1f(v);
                }
            }
#pragma unroll
            for (int i = 0; i < 4; ++i) {
                int r  = i * 4 + quad;           // 0..15
                int cv = l16;                    // 16B chunk (8 values)
                const float* tp = &T[r * TPAD + cv * 8];
                float4 t0 = *(const float4*)tp;
                float4 t1 = *(const float4*)(tp + 4);
                ushort4 o0, o1;
                o0.x = f2bf(t0.x); o0.y = f2bf(t0.y); o0.z = f2bf(t0.z); o0.w = f2bf(t0.w);
                o1.x = f2bf(t1.x); o1.y = f2bf(t1.y); o1.z = f2bf(t1.z); o1.w = f2bf(t1.w);
                ushort* dstp = &hout[(trow0 + r) * CC + cv * 8];
                *(ushort4*)dstp = o0;
                *(ushort4*)(dstp + 4) = o1;
            }
        }
    }
}

extern "C" void kernel_launch(void* const* d_in, const int* in_sizes, int n_in,
                              void* d_out, int out_size, void* d_ws, size_t ws_size,
                              hipStream_t stream) {
    const float* x   = (const float*)d_in[0];
    const int*   ei  = (const int*)d_in[1];
    const int*   src = ei;
    const int*   dst = ei + EE;
    const float* w0a = (const float*)d_in[2];
    const float* b0a = (const float*)d_in[3];
    const float* w0b = (const float*)d_in[4];
    const float* b0b = (const float*)d_in[5];
    const float* w1a = (const float*)d_in[6];
    const float* b1a = (const float*)d_in[7];
    const float* w1b = (const float*)d_in[8];
    const float* b1b = (const float*)d_in[9];
    const float* w2a = (const float*)d_in[10];
    const float* b2a = (const float*)d_in[11];
    const float* w2b = (const float*)d_in[12];
    const float* b2b = (const float*)d_in[13];
    const float* lw  = (const float*)d_in[14];
    const float* lb  = (const float*)d_in[15];
    float* outp = (float*)d_out;

    // workspace layout (3 activation buffers: xb reused as layer-2 output)
    ushort* xb  = (ushort*)d_ws;                      // N*CC bf16
    ushort* hbA = xb + (size_t)NN * CC;               // N*CC bf16
    ushort* agg = hbA + (size_t)NN * CC;              // N*CC bf16
    ushort* wT  = agg + (size_t)NN * CC;              // 6 * 128*128 bf16
    int* col    = (int*)(wT + 6 * CC * CC);           // EE
    int* rowptr    = col + EE;                        // NN+1
    int* cursor    = rowptr + NN + 1;                 // NN
    int* deg       = cursor + NN;                     // NN
    int* bucketCnt = deg + NN;                        // 8  (memset together with deg)
    int* blockSums = bucketCnt + NRANGE;              // NB_SCAN
    int* blockOff  = blockSums + NB_SCAN;             // NB_SCAN
    int* padp      = blockOff + NB_SCAN;              // align to 8B for int2
    uintptr_t bbAddr = ((uintptr_t)padp + 7) & ~(uintptr_t)7;
    int2* bucketBuf = (int2*)bbAddr;                  // 8 * BUCKET_CAP int2

    ushort* w0aT = wT;
    ushort* w0bT = wT + 1 * CC * CC;
    ushort* w1aT = wT + 2 * CC * CC;
    ushort* w1bT = wT + 3 * CC * CC;
    ushort* w2aT = wT + 4 * CC * CC;
    ushort* w2bT = wT + 5 * CC * CC;

    const int gatherBlocks = NN / 16;                 // 6250
    const int mlpBlocks    = (NN / 32 + 3) / 4;       // 782 (4 waves x 32 rows)
    const int cvtXBlocks   = (NN * CC / 4) / 256;

    // ---- conversions ----
    convert_x_kernel<<<cvtXBlocks, 256, 0, stream>>>(x, xb);
    convert_w6_kernel<<<6 * 64, 256, 0, stream>>>(w0a, w0b, w1a, w1b, w2a, w2b, wT);

    // ---- CSR build: bucket -> hist -> scan -> fill ----
    hipMemsetAsync(deg, 0, (NN + NRANGE) * sizeof(int), stream);  // deg + bucketCnt
    bucket_edges<<<NCHUNKS, 256, 0, stream>>>(src, dst, bucketCnt, bucketBuf);
    hist_bucket<<<RB * NRANGE, 256, 0, stream>>>(bucketBuf, bucketCnt, deg);
    deg_block_reduce<<<NB_SCAN, 256, 0, stream>>>(deg, blockSums);
    scan_offsets<<<1, 64, 0, stream>>>(blockSums, blockOff, rowptr);
    deg_scan_write<<<NB_SCAN, 256, 0, stream>>>(deg, blockOff, rowptr, cursor);
    fill_bucket<<<RB * NRANGE, 256, 0, stream>>>(bucketBuf, bucketCnt, cursor, col);

    // ---- layer 1 ----
    gather_agg<<<gatherBlocks, 256, 0, stream>>>(xb, rowptr, col, agg);
    mlp_wave2<false><<<mlpBlocks, 256, 0, stream>>>(agg, w0aT, b0a, w0bT, b0b, hbA,
                                                    nullptr, nullptr, nullptr);
    // ---- layer 2 (output into xb, no longer needed) ----
    gather_agg<<<gatherBlocks, 256, 0, stream>>>(hbA, rowptr, col, agg);
    mlp_wave2<false><<<mlpBlocks, 256, 0, stream>>>(agg, w1aT, b1a, w1bT, b1b, xb,
                                                    nullptr, nullptr, nullptr);
    // ---- layer 3 + fused head ----
    gather_agg<<<gatherBlocks, 256, 0, stream>>>(xb, rowptr, col, agg);
    mlp_wave2<true><<<mlpBlocks, 256, 0, stream>>>(agg, w2aT, b2a, w2bT, b2b, nullptr,
                                                   lw, lb, outp);
}

// Round 9
// 599.801 us; speedup vs baseline: 1.1101x; 1.1101x over previous
//
#include <hip/hip_runtime.h>
#include <hip/hip_bf16.h>
#include <math.h>

#define NN 100000
#define CC 128
#define EE 1600000
#define SCAN_CHUNK 2048
#define NB_SCAN ((NN + SCAN_CHUNK - 1) / SCAN_CHUNK)  // 49
#define NRANGE 8
#define RNODES (NN / NRANGE)     // 12500
#define EPT 8                    // edges per thread in partitioned edge kernels
#define FCHUNK (256 * EPT)       // 2048 edges per block
#define NCHUNKS ((EE + FCHUNK - 1) / FCHUNK)  // 782

typedef short  bf16x8 __attribute__((ext_vector_type(8)));
typedef float  f32x4  __attribute__((ext_vector_type(4)));
typedef int    i32x4  __attribute__((ext_vector_type(4)));
typedef unsigned short u16x8 __attribute__((ext_vector_type(8)));

#define TPAD 132   // float stride for per-wave T tiles (528 B, 16B-aligned)

__device__ __forceinline__ ushort f2bf(float f) {
    __hip_bfloat16 h = __float2bfloat16(f);   // RNE
    return __builtin_bit_cast(ushort, h);
}
__device__ __forceinline__ float bf2f(ushort u) {
    return __builtin_bit_cast(float, ((unsigned int)u) << 16);
}

// ===========================================================================
// CSR build (dst-partitioned by XCD range; edge-list reads NON-TEMPORAL so
// the 8x streaming re-scan doesn't evict the partially-dirty col/deg lines)
// ===========================================================================
__global__ void __launch_bounds__(256) hist_part(
    const int* __restrict__ dst, int* __restrict__ deg)
{
    int range = blockIdx.x & (NRANGE - 1);
    int chunk = blockIdx.x >> 3;
    int lo = range * RNODES, hi = lo + RNODES;
    int base = chunk * FCHUNK + threadIdx.x * EPT;
    if (base + EPT <= EE) {
        i32x4 d0 = __builtin_nontemporal_load((const i32x4*)&dst[base]);
        i32x4 d1 = __builtin_nontemporal_load((const i32x4*)&dst[base + 4]);
        int dd[8] = {d0[0], d0[1], d0[2], d0[3], d1[0], d1[1], d1[2], d1[3]};
#pragma unroll
        for (int i = 0; i < 8; ++i) {
            int d = dd[i];
            if (d >= lo && d < hi) atomicAdd(&deg[d], 1);
        }
    } else {
        for (int i = 0; i < EPT; ++i) {
            int e = base + i;
            if (e < EE) {
                int d = dst[e];
                if (d >= lo && d < hi) atomicAdd(&deg[d], 1);
            }
        }
    }
}

__global__ void __launch_bounds__(256) deg_block_reduce(
    const int* __restrict__ deg, int* __restrict__ blockSums)
{
    int base = blockIdx.x * SCAN_CHUNK + threadIdx.x * 8;
    int s = 0;
#pragma unroll
    for (int i = 0; i < 8; ++i) {
        int idx = base + i;
        if (idx < NN) s += deg[idx];
    }
#pragma unroll
    for (int off = 32; off > 0; off >>= 1) s += __shfl_down(s, off);
    __shared__ int ws[4];
    int lane = threadIdx.x & 63, wid = threadIdx.x >> 6;
    if (lane == 0) ws[wid] = s;
    __syncthreads();
    if (threadIdx.x == 0) blockSums[blockIdx.x] = ws[0] + ws[1] + ws[2] + ws[3];
}

__global__ void scan_offsets(const int* __restrict__ blockSums,
                             int* __restrict__ blockOff, int* __restrict__ rowptr)
{
    int lane = threadIdx.x;  // 64 threads
    int v = (lane < NB_SCAN) ? blockSums[lane] : 0;
    int inc = v;
#pragma unroll
    for (int off = 1; off < 64; off <<= 1) {
        int n = __shfl_up(inc, off);
        if (lane >= off) inc += n;
    }
    if (lane < NB_SCAN) blockOff[lane] = inc - v;
    if (lane == 63) rowptr[NN] = EE;
}

__global__ void __launch_bounds__(256) deg_scan_write(
    const int* __restrict__ deg, const int* __restrict__ blockOff,
    int* __restrict__ rowptr, int* __restrict__ cursor)
{
    __shared__ int warpSums[4];
    int base = blockIdx.x * SCAN_CHUNK + threadIdx.x * 8;
    int v[8];
    int s = 0;
#pragma unroll
    for (int i = 0; i < 8; ++i) {
        int idx = base + i;
        v[i] = (idx < NN) ? deg[idx] : 0;
        s += v[i];
    }
    int lane = threadIdx.x & 63, wid = threadIdx.x >> 6;
    int inc = s;
#pragma unroll
    for (int off = 1; off < 64; off <<= 1) {
        int n = __shfl_up(inc, off);
        if (lane >= off) inc += n;
    }
    if (lane == 63) warpSums[wid] = inc;
    __syncthreads();
    int wofs = 0;
#pragma unroll
    for (int w = 0; w < 4; ++w)
        if (w < wid) wofs += warpSums[w];
    int exc = blockOff[blockIdx.x] + wofs + (inc - s);
#pragma unroll
    for (int i = 0; i < 8; ++i) {
        int idx = base + i;
        if (idx < NN) { rowptr[idx] = exc; cursor[idx] = exc; }
        exc += v[i];
    }
}

__global__ void __launch_bounds__(256) fill_csr_part(
    const int* __restrict__ src, const int* __restrict__ dst,
    int* __restrict__ cursor, int* __restrict__ col)
{
    int range = blockIdx.x & (NRANGE - 1);
    int chunk = blockIdx.x >> 3;
    int lo = range * RNODES, hi = lo + RNODES;
    int base = chunk * FCHUNK + threadIdx.x * EPT;
    if (base + EPT <= EE) {
        i32x4 d0 = __builtin_nontemporal_load((const i32x4*)&dst[base]);
        i32x4 d1 = __builtin_nontemporal_load((const i32x4*)&dst[base + 4]);
        i32x4 s0 = __builtin_nontemporal_load((const i32x4*)&src[base]);
        i32x4 s1 = __builtin_nontemporal_load((const i32x4*)&src[base + 4]);
        int dd[8] = {d0[0], d0[1], d0[2], d0[3], d1[0], d1[1], d1[2], d1[3]};
        int ss[8] = {s0[0], s0[1], s0[2], s0[3], s1[0], s1[1], s1[2], s1[3]};
#pragma unroll
        for (int i = 0; i < 8; ++i) {
            int d = dd[i];
            if (d >= lo && d < hi) {
                int pos = atomicAdd(&cursor[d], 1);
                col[pos] = ss[i];
            }
        }
    } else {
        for (int i = 0; i < EPT; ++i) {
            int e = base + i;
            if (e < EE) {
                int d = dst[e];
                if (d >= lo && d < hi) {
                    int s = src[e];
                    int pos = atomicAdd(&cursor[d], 1);
                    col[pos] = s;
                }
            }
        }
    }
}

// ===========================================================================
// Conversions
// ===========================================================================
__global__ void __launch_bounds__(256) convert_x_kernel(
    const float* __restrict__ x, ushort* __restrict__ xb)
{
    int i = blockIdx.x * 256 + threadIdx.x;   // float4 groups; NN*CC/4 total
    f32x4 v = __builtin_nontemporal_load((const f32x4*)x + i);  // single-use stream
    ushort4 o;
    o.x = f2bf(v[0]); o.y = f2bf(v[1]); o.z = f2bf(v[2]); o.w = f2bf(v[3]);
    ((ushort4*)xb)[i] = o;
}

__global__ void __launch_bounds__(256) convert_w6_kernel(
    const float* __restrict__ w0, const float* __restrict__ w1,
    const float* __restrict__ w2, const float* __restrict__ w3,
    const float* __restrict__ w4, const float* __restrict__ w5,
    ushort* __restrict__ wt)
{
    int i = blockIdx.x * 256 + threadIdx.x;  // 6*16384
    int mat = i >> 14;
    int rem = i & 16383;
    int k = rem >> 7, n = rem & 127;
    const float* w = (mat == 0) ? w0 : (mat == 1) ? w1 : (mat == 2) ? w2
                   : (mat == 3) ? w3 : (mat == 4) ? w4 : w5;
    wt[mat * 16384 + n * 128 + k] = f2bf(w[k * 128 + n]);
}

// ===========================================================================
// Standalone max-occupancy gather: agg[n] = h[n] + sum_nbr h[nbr]  (bf16)
// ===========================================================================
__global__ void __launch_bounds__(256) gather_agg(
    const ushort* __restrict__ hin, const int* __restrict__ rowptr,
    const int* __restrict__ col, ushort* __restrict__ agg)
{
    const int grp    = threadIdx.x >> 4;            // 0..15
    const int lane16 = threadIdx.x & 15;
    const int gbase  = (threadIdx.x & 63) & 48;     // group base lane in wave
    const int n = blockIdx.x * 16 + grp;            // 6250*16 = 100000 exact
    const u16x8* hp = (const u16x8*)hin;

    u16x8 self = hp[n * 16 + lane16];
    float s0[8], s1[8], s2[8], s3[8];
#pragma unroll
    for (int k = 0; k < 8; ++k) {
        s0[k] = bf2f(self[k]); s1[k] = 0.f; s2[k] = 0.f; s3[k] = 0.f;
    }

    int beg = rowptr[n], end = rowptr[n + 1];
    while (beg < end) {
        int take = end - beg;
        if (take > 16) take = 16;
        int ci = (lane16 < take) ? col[beg + lane16] : 0;
        int j = 0;
        for (; j + 4 <= take; j += 4) {
            int n0 = __shfl(ci, gbase + j + 0);
            int n1 = __shfl(ci, gbase + j + 1);
            int n2 = __shfl(ci, gbase + j + 2);
            int n3 = __shfl(ci, gbase + j + 3);
            u16x8 a0 = hp[n0 * 16 + lane16];
            u16x8 a1 = hp[n1 * 16 + lane16];
            u16x8 a2 = hp[n2 * 16 + lane16];
            u16x8 a3 = hp[n3 * 16 + lane16];
#pragma unroll
            for (int k = 0; k < 8; ++k) {
                s0[k] += bf2f(a0[k]); s1[k] += bf2f(a1[k]);
                s2[k] += bf2f(a2[k]); s3[k] += bf2f(a3[k]);
            }
        }
        for (; j < take; ++j) {
            int n0 = __shfl(ci, gbase + j);
            u16x8 a0 = hp[n0 * 16 + lane16];
#pragma unroll
            for (int k = 0; k < 8; ++k) s0[k] += bf2f(a0[k]);
        }
        beg += take;
    }

    bf16x8 o;
#pragma unroll
    for (int k = 0; k < 8; ++k) o[k] = (short)f2bf(s0[k] + s1[k] + s2[k] + s3[k]);
    *(bf16x8*)&((ushort*)agg)[n * CC + lane16 * 8] = o;
}

// ===========================================================================
// Barrier-free 2-tile per-wave MFMA MLP: each wave owns 32 rows (2 M-tiles).
// Every B-fragment load feeds 2 MFMAs. Per-wave private LDS T tile.
// ===========================================================================
template <bool FUSE_HEAD>
__global__ void __launch_bounds__(256, 4) mlp_wave2(
    const ushort* __restrict__ hin,
    const ushort* __restrict__ waT, const float* __restrict__ ba,
    const ushort* __restrict__ wbT, const float* __restrict__ bb,
    ushort* __restrict__ hout,
    const float* __restrict__ lw, const float* __restrict__ lb,
    float* __restrict__ out)
{
    __shared__ float Tt[4][16 * TPAD];   // per-wave private 16x128 fp32 tile

    const int wave = threadIdx.x >> 6;
    const int lane = threadIdx.x & 63;
    const int quad = lane >> 4;
    const int l16  = lane & 15;
    const int wv = blockIdx.x * 4 + wave;       // wave index; each owns 32 rows
    if (wv * 32 >= NN) return;                  // NN % 32 == 0: all-or-nothing
    const int row0 = wv * 32;
    float* T = Tt[wave];

    // ---- stage-1 A fragments straight from global, both tiles ----
    bf16x8 af0[4], af1[4];
#pragma unroll
    for (int kk = 0; kk < 4; ++kk) {
        af0[kk] = *(const bf16x8*)&hin[(row0 + l16) * CC + kk * 32 + quad * 8];
        af1[kk] = *(const bf16x8*)&hin[(row0 + 16 + l16) * CC + kk * 32 + quad * 8];
    }

    // ---- stage 1: T = relu(A @ Wa + ba), shared B-frag for both tiles ----
    f32x4 acc0[8], acc1[8];
#pragma unroll
    for (int nt = 0; nt < 8; ++nt) {
        acc0[nt] = (f32x4){0.f, 0.f, 0.f, 0.f};
        acc1[nt] = (f32x4){0.f, 0.f, 0.f, 0.f};
    }
#pragma unroll
    for (int kk = 0; kk < 4; ++kk) {
#pragma unroll
        for (int nt = 0; nt < 8; ++nt) {
            bf16x8 bfrag = *(const bf16x8*)&waT[(nt * 16 + l16) * CC + kk * 32 + quad * 8];
            acc0[nt] = __builtin_amdgcn_mfma_f32_16x16x32_bf16(af0[kk], bfrag, acc0[nt], 0, 0, 0);
            acc1[nt] = __builtin_amdgcn_mfma_f32_16x16x32_bf16(af1[kk], bfrag, acc1[nt], 0, 0, 0);
        }
    }

    // ---- C-layout -> A-layout via per-wave T, sequential per tile ----
    bf16x8 a20[4], a21[4];
#pragma unroll
    for (int t = 0; t < 2; ++t) {
#pragma unroll
        for (int nt = 0; nt < 8; ++nt) {
            int colc = nt * 16 + l16;
            float bias = ba[colc];
#pragma unroll
            for (int r = 0; r < 4; ++r) {
                float v = (t == 0 ? acc0[nt][r] : acc1[nt][r]) + bias;
                T[(quad * 4 + r) * TPAD + colc] = fmaxf(v, 0.f);
            }
        }
        // within-wave LDS write->read ordering (compiler lgkmcnt), no barrier
#pragma unroll
        for (int kk = 0; kk < 4; ++kk) {
            const float* tp = &T[l16 * TPAD + kk * 32 + quad * 8];
            float4 t0 = *(const float4*)tp;
            float4 t1 = *(const float4*)(tp + 4);
            bf16x8 f;
            f[0] = (short)f2bf(t0.x); f[1] = (short)f2bf(t0.y);
            f[2] = (short)f2bf(t0.z); f[3] = (short)f2bf(t0.w);
            f[4] = (short)f2bf(t1.x); f[5] = (short)f2bf(t1.y);
            f[6] = (short)f2bf(t1.z); f[7] = (short)f2bf(t1.w);
            if (t == 0) a20[kk] = f; else a21[kk] = f;
        }
    }

    // ---- stage 2: out = elu(T @ Wb + bb), shared B-frag for both tiles ----
    f32x4 bcc0[8], bcc1[8];
#pragma unroll
    for (int nt = 0; nt < 8; ++nt) {
        bcc0[nt] = (f32x4){0.f, 0.f, 0.f, 0.f};
        bcc1[nt] = (f32x4){0.f, 0.f, 0.f, 0.f};
    }
#pragma unroll
    for (int kk = 0; kk < 4; ++kk) {
#pragma unroll
        for (int nt = 0; nt < 8; ++nt) {
            bf16x8 bfrag = *(const bf16x8*)&wbT[(nt * 16 + l16) * CC + kk * 32 + quad * 8];
            bcc0[nt] = __builtin_amdgcn_mfma_f32_16x16x32_bf16(a20[kk], bfrag, bcc0[nt], 0, 0, 0);
            bcc1[nt] = __builtin_amdgcn_mfma_f32_16x16x32_bf16(a21[kk], bfrag, bcc1[nt], 0, 0, 0);
        }
    }

#pragma unroll
    for (int t = 0; t < 2; ++t) {
        const int trow0 = row0 + t * 16;
        if (FUSE_HEAD) {
            float part[4] = {0.f, 0.f, 0.f, 0.f};
#pragma unroll
            for (int nt = 0; nt < 8; ++nt) {
                int colc = nt * 16 + l16;
                float bias = bb[colc];
                float w = lw[colc];
#pragma unroll
                for (int r = 0; r < 4; ++r) {
                    float v = (t == 0 ? bcc0[nt][r] : bcc1[nt][r]) + bias;
                    v = v > 0.f ? v : expm1f(v);
                    part[r] += v * w;
                }
            }
#pragma unroll
            for (int r = 0; r < 4; ++r) {
#pragma unroll
                for (int off = 8; off > 0; off >>= 1)
                    part[r] += __shfl_xor(part[r], off);
            }
            if (l16 == 0) {
                float lbv = lb[0];
#pragma unroll
                for (int r = 0; r < 4; ++r) {
                    int grow = trow0 + quad * 4 + r;
                    float z = part[r] + lbv;
                    out[grow] = 1.f / (1.f + expf(-z));
                }
            }
        } else {
            // elu -> T (safe: same wave done with a2 reads) -> coalesced store
#pragma unroll
            for (int nt = 0; nt < 8; ++nt) {
                int colc = nt * 16 + l16;
                float bias = bb[colc];
#pragma unroll
                for (int r = 0; r < 4; ++r) {
                    float v = (t == 0 ? bcc0[nt][r] : bcc1[nt][r]) + bias;
                    T[(quad * 4 + r) * TPAD + colc] = v > 0.f ? v : expm1f(v);
                }
            }
#pragma unroll
            for (int i = 0; i < 4; ++i) {
                int r  = i * 4 + quad;           // 0..15
                int cv = l16;                    // 16B chunk (8 values)
                const float* tp = &T[r * TPAD + cv * 8];
                float4 t0 = *(const float4*)tp;
                float4 t1 = *(const float4*)(tp + 4);
                ushort4 o0, o1;
                o0.x = f2bf(t0.x); o0.y = f2bf(t0.y); o0.z = f2bf(t0.z); o0.w = f2bf(t0.w);
                o1.x = f2bf(t1.x); o1.y = f2bf(t1.y); o1.z = f2bf(t1.z); o1.w = f2bf(t1.w);
                ushort* dstp = &hout[(trow0 + r) * CC + cv * 8];
                *(ushort4*)dstp = o0;
                *(ushort4*)(dstp + 4) = o1;
            }
        }
    }
}

extern "C" void kernel_launch(void* const* d_in, const int* in_sizes, int n_in,
                              void* d_out, int out_size, void* d_ws, size_t ws_size,
                              hipStream_t stream) {
    const float* x   = (const float*)d_in[0];
    const int*   ei  = (const int*)d_in[1];
    const int*   src = ei;
    const int*   dst = ei + EE;
    const float* w0a = (const float*)d_in[2];
    const float* b0a = (const float*)d_in[3];
    const float* w0b = (const float*)d_in[4];
    const float* b0b = (const float*)d_in[5];
    const float* w1a = (const float*)d_in[6];
    const float* b1a = (const float*)d_in[7];
    const float* w1b = (const float*)d_in[8];
    const float* b1b = (const float*)d_in[9];
    const float* w2a = (const float*)d_in[10];
    const float* b2a = (const float*)d_in[11];
    const float* w2b = (const float*)d_in[12];
    const float* b2b = (const float*)d_in[13];
    const float* lw  = (const float*)d_in[14];
    const float* lb  = (const float*)d_in[15];
    float* outp = (float*)d_out;

    // workspace layout (3 activation buffers: xb reused as layer-2 output)
    ushort* xb  = (ushort*)d_ws;                      // N*CC bf16
    ushort* hbA = xb + (size_t)NN * CC;               // N*CC bf16
    ushort* agg = hbA + (size_t)NN * CC;              // N*CC bf16
    ushort* wT  = agg + (size_t)NN * CC;              // 6 * 128*128 bf16
    int* col    = (int*)(wT + 6 * CC * CC);           // EE
    int* rowptr    = col + EE;                        // NN+1
    int* cursor    = rowptr + NN + 1;                 // NN
    int* deg       = cursor + NN;                     // NN
    int* blockSums = deg + NN;                        // NB_SCAN
    int* blockOff  = blockSums + NB_SCAN;             // NB_SCAN

    ushort* w0aT = wT;
    ushort* w0bT = wT + 1 * CC * CC;
    ushort* w1aT = wT + 2 * CC * CC;
    ushort* w1bT = wT + 3 * CC * CC;
    ushort* w2aT = wT + 4 * CC * CC;
    ushort* w2bT = wT + 5 * CC * CC;

    const int gatherBlocks = NN / 16;                 // 6250
    const int mlpBlocks    = (NN / 32 + 3) / 4;       // 782 (4 waves x 32 rows)
    const int cvtXBlocks   = (NN * CC / 4) / 256;

    // ---- conversions ----
    convert_x_kernel<<<cvtXBlocks, 256, 0, stream>>>(x, xb);
    convert_w6_kernel<<<6 * 64, 256, 0, stream>>>(w0a, w0b, w1a, w1b, w2a, w2b, wT);

    // ---- CSR build ----
    hipMemsetAsync(deg, 0, NN * sizeof(int), stream);
    hist_part<<<NCHUNKS * NRANGE, 256, 0, stream>>>(dst, deg);
    deg_block_reduce<<<NB_SCAN, 256, 0, stream>>>(deg, blockSums);
    scan_offsets<<<1, 64, 0, stream>>>(blockSums, blockOff, rowptr);
    deg_scan_write<<<NB_SCAN, 256, 0, stream>>>(deg, blockOff, rowptr, cursor);
    fill_csr_part<<<NCHUNKS * NRANGE, 256, 0, stream>>>(src, dst, cursor, col);

    // ---- layer 1 ----
    gather_agg<<<gatherBlocks, 256, 0, stream>>>(xb, rowptr, col, agg);
    mlp_wave2<false><<<mlpBlocks, 256, 0, stream>>>(agg, w0aT, b0a, w0bT, b0b, hbA,
                                                    nullptr, nullptr, nullptr);
    // ---- layer 2 (output into xb, no longer needed) ----
    gather_agg<<<gatherBlocks, 256, 0, stream>>>(hbA, rowptr, col, agg);
    mlp_wave2<false><<<mlpBlocks, 256, 0, stream>>>(agg, w1aT, b1a, w1bT, b1b, xb,
                                                    nullptr, nullptr, nullptr);
    // ---- layer 3 + fused head ----
    gather_agg<<<gatherBlocks, 256, 0, stream>>>(xb, rowptr, col, agg);
    mlp_wave2<true><<<mlpBlocks, 256, 0, stream>>>(agg, w2aT, b2a, w2bT, b2b, nullptr,
                                                   lw, lb, outp);
}